// Round 8
// baseline (312.436 us; speedup 1.0000x reference)
//
#include <hip/hip_runtime.h>
#include <hip/hip_bf16.h>
#include <math.h>

#define B_      8
#define CIN     256
#define CMID    512
#define COUT    256
#define N_      2048
#define SCALE_  10.0f
#define EPS_THR 1e-3f
#define NORM_EPS_ 1e-12f

typedef __attribute__((ext_vector_type(8))) short short8;
typedef __attribute__((ext_vector_type(4))) float f32x4;

__device__ __forceinline__ ushort f2bf(float x) {
    union { float f; uint u; } v; v.f = x;
    uint r = v.u + 0x7FFF + ((v.u >> 16) & 1);
    return (ushort)(r >> 16);
}
__device__ __forceinline__ void gload_lds16(const void* g, void* l) {
    __builtin_amdgcn_global_load_lds((const __attribute__((address_space(1))) void*)g,
                                     (__attribute__((address_space(3))) void*)l, 16, 0, 0);
}

// ---------------- K0: weights fp32 -> bf16 ------------------------------------------
__global__ __launch_bounds__(256) void prep_w(const float* __restrict__ W1,
                                              const float* __restrict__ W2,
                                              ushort* __restrict__ W1b,
                                              ushort* __restrict__ W2b) {
    int idx = blockIdx.x * 256 + threadIdx.x;   // 0..131071
    W1b[idx] = f2bf(W1[idx]);
    W2b[idx] = f2bf(W2[idx]);
}

// ---------------- K1: conv1 fused with input transpose ------------------------------
#define ASTRIDE 40
__global__ __launch_bounds__(512) void conv1_fused(const float* __restrict__ q,
                                                   const float* __restrict__ k,
                                                   const ushort* __restrict__ W1b,
                                                   ushort* __restrict__ H) {
    __shared__ ushort As[64 * ASTRIDE];   // 5 KB, padded stride
    __shared__ ushort Bs[512 * 32];       // 32 KB
    int tid = threadIdx.x;
    int lane = tid & 63, wave = tid >> 6;
    int g = lane >> 4, cl = lane & 15;
    size_t m0 = (size_t)blockIdx.x * 64;
    const float* xsrc = (m0 < 16384) ? q : k;
    int b = (int)((m0 >> 11) & 7);
    int nbase = (int)(m0 & 2047);
    const float* xp = xsrc + ((size_t)b * CIN + wave * 4) * N_ + nbase + lane;

    f32x4 acc[4][4];
#pragma unroll
    for (int i = 0; i < 4; ++i)
#pragma unroll
        for (int j = 0; j < 4; ++j) acc[i][j] = (f32x4)0.f;

    for (int k0 = 0; k0 < CIN; k0 += 32) {
#pragma unroll
        for (int si = 0; si < 4; ++si) {
            int s = tid + si * 512;
            gload_lds16(W1b + (size_t)(s >> 2) * CIN + k0 + (s & 3) * 8, Bs + s * 8);
        }
        float v0 = xp[(size_t)(k0 + 0) * N_];
        float v1 = xp[(size_t)(k0 + 1) * N_];
        float v2 = xp[(size_t)(k0 + 2) * N_];
        float v3 = xp[(size_t)(k0 + 3) * N_];
        ushort4 wv;
        wv.x = f2bf(v0); wv.y = f2bf(v1); wv.z = f2bf(v2); wv.w = f2bf(v3);
        *(ushort4*)&As[lane * ASTRIDE + wave * 4] = wv;
        __syncthreads();

        short8 af[4], bfr[4];
#pragma unroll
        for (int mi = 0; mi < 4; ++mi)
            af[mi] = *(const short8*)&As[(mi * 16 + cl) * ASTRIDE + g * 8];
#pragma unroll
        for (int ni = 0; ni < 4; ++ni)
            bfr[ni] = *(const short8*)&Bs[(wave * 64 + ni * 16 + cl) * 32 + g * 8];
#pragma unroll
        for (int mi = 0; mi < 4; ++mi)
#pragma unroll
            for (int ni = 0; ni < 4; ++ni)
                acc[mi][ni] = __builtin_amdgcn_mfma_f32_16x16x32_bf16(af[mi], bfr[ni], acc[mi][ni], 0, 0, 0);
        __syncthreads();
    }

#pragma unroll
    for (int mi = 0; mi < 4; ++mi)
#pragma unroll
        for (int ni = 0; ni < 4; ++ni)
#pragma unroll
            for (int r = 0; r < 4; ++r) {
                float v = acc[mi][ni][r];
                v = (v >= 0.f) ? v : 0.01f * v;
                H[(m0 + mi * 16 + g * 4 + r) * CMID + wave * 64 + ni * 16 + cl] = f2bf(v);
            }
}

// ---------------- K2: conv2 fused with row L2-norm ----------------------------------
__global__ __launch_bounds__(512) void conv2_norm(const ushort* __restrict__ H,
                                                  const ushort* __restrict__ W2b,
                                                  ushort* __restrict__ QK) {
    __shared__ ushort As[128 * 32];   // 8 KB
    __shared__ ushort Bs[256 * 32];   // 16 KB
    __shared__ float red[4][128];     // 2 KB
    int tid = threadIdx.x;
    int lane = tid & 63, wave = tid >> 6;
    int wm = wave >> 2, wn = wave & 3;
    int g = lane >> 4, cl = lane & 15;
    size_t m0 = (size_t)blockIdx.x * 128;

    f32x4 acc[4][4];
#pragma unroll
    for (int i = 0; i < 4; ++i)
#pragma unroll
        for (int j = 0; j < 4; ++j) acc[i][j] = (f32x4)0.f;

    for (int k0 = 0; k0 < CMID; k0 += 32) {
        gload_lds16(H + (m0 + (tid >> 2)) * CMID + k0 + (tid & 3) * 8, As + tid * 8);
#pragma unroll
        for (int si = 0; si < 2; ++si) {
            int s = tid + si * 512;
            gload_lds16(W2b + (size_t)(s >> 2) * CMID + k0 + (s & 3) * 8, Bs + s * 8);
        }
        __syncthreads();
        short8 af[4], bfr[4];
#pragma unroll
        for (int mi = 0; mi < 4; ++mi)
            af[mi] = *(const short8*)&As[(wm * 64 + mi * 16 + cl) * 32 + g * 8];
#pragma unroll
        for (int ni = 0; ni < 4; ++ni)
            bfr[ni] = *(const short8*)&Bs[(wn * 64 + ni * 16 + cl) * 32 + g * 8];
#pragma unroll
        for (int mi = 0; mi < 4; ++mi)
#pragma unroll
            for (int ni = 0; ni < 4; ++ni)
                acc[mi][ni] = __builtin_amdgcn_mfma_f32_16x16x32_bf16(af[mi], bfr[ni], acc[mi][ni], 0, 0, 0);
        __syncthreads();
    }

#pragma unroll
    for (int mi = 0; mi < 4; ++mi)
#pragma unroll
        for (int r = 0; r < 4; ++r) {
            float s = 0.f;
#pragma unroll
            for (int ni = 0; ni < 4; ++ni) { float v = acc[mi][ni][r]; s += v * v; }
#pragma unroll
            for (int off = 1; off < 16; off <<= 1) s += __shfl_xor(s, off, 64);
            if (cl == 0) red[wn][wm * 64 + mi * 16 + g * 4 + r] = s;
        }
    __syncthreads();
#pragma unroll
    for (int mi = 0; mi < 4; ++mi)
#pragma unroll
        for (int r = 0; r < 4; ++r) {
            int row = wm * 64 + mi * 16 + g * 4 + r;
            float tot = red[0][row] + red[1][row] + red[2][row] + red[3][row];
            float inv = 1.0f / fmaxf(sqrtf(tot), NORM_EPS_);
#pragma unroll
            for (int ni = 0; ni < 4; ++ni)
                QK[(m0 + row) * COUT + wn * 64 + ni * 16 + cl] = f2bf(acc[mi][ni][r] * inv);
        }
}

// ---------------- K3: fused scores + softmax(fixed max) + threshold -----------------
// Two-pass recompute, 64 q-rows x 2048 k-cols per block, 8 waves (wave w -> cols
// w*256..+255). |q|=|k|=1 => scores<=10 => fixed shift (softmax shift-invariant).
// Pass 1: MFMA + exp -> row sums only (nothing stored). Pass 2: reload B (now
// XCD-L2-hot), recompute, scale, threshold, store. No e-storage => no LDS cap,
// and K-panel L3 reads halve vs 32-row blocks (256 MB total).
__global__ __launch_bounds__(512, 2) __attribute__((amdgpu_waves_per_eu(2, 2)))
void scores_softmax(const ushort* __restrict__ QK, float* __restrict__ out) {
    __shared__ float red[8][64];     // 2 KB
    int bid = blockIdx.x;
    int b = bid & 7;                 // batch-per-XCD swizzle (256 blocks, 32/XCD)
    int m0 = (bid >> 3) * 64;
    int tid = threadIdx.x;
    int lane = tid & 63, wave = tid >> 6;
    int g = lane >> 4, cl = lane & 15;

    const ushort* Qb = QK + ((size_t)b * N_ + m0) * COUT;
    const ushort* Kb = QK + ((size_t)16384 + (size_t)b * N_ + wave * 256) * COUT;

    short8 af[4][8];                 // 128 VGPR resident
#pragma unroll
    for (int mi = 0; mi < 4; ++mi)
#pragma unroll
        for (int ks = 0; ks < 8; ++ks)
            af[mi][ks] = *(const short8*)(Qb + (size_t)(mi * 16 + cl) * COUT + ks * 32 + g * 8);

    float rs[4][4];
#pragma unroll
    for (int mi = 0; mi < 4; ++mi)
#pragma unroll
        for (int r = 0; r < 4; ++r) rs[mi][r] = 0.f;

    // ---- pass 1: row sums ----
#pragma unroll
    for (int ct = 0; ct < 16; ++ct) {
        short8 bfr[8];
#pragma unroll
        for (int ks = 0; ks < 8; ++ks)
            bfr[ks] = *(const short8*)(Kb + (size_t)(ct * 16 + cl) * COUT + ks * 32 + g * 8);
        f32x4 a[4];
#pragma unroll
        for (int mi = 0; mi < 4; ++mi) a[mi] = (f32x4)0.f;
#pragma unroll
        for (int ks = 0; ks < 8; ++ks)
#pragma unroll
            for (int mi = 0; mi < 4; ++mi)
                a[mi] = __builtin_amdgcn_mfma_f32_16x16x32_bf16(af[mi][ks], bfr[ks], a[mi], 0, 0, 0);
#pragma unroll
        for (int mi = 0; mi < 4; ++mi)
#pragma unroll
            for (int r = 0; r < 4; ++r)
                rs[mi][r] += __expf((a[mi][r] - 1.0f) * SCALE_);
    }

    // reduce over 16 cl lanes, then across 8 waves via LDS
#pragma unroll
    for (int mi = 0; mi < 4; ++mi)
#pragma unroll
        for (int r = 0; r < 4; ++r) {
            float s = rs[mi][r];
#pragma unroll
            for (int off = 1; off < 16; off <<= 1) s += __shfl_xor(s, off, 64);
            if (cl == 0) red[wave][mi * 16 + g * 4 + r] = s;
        }
    __syncthreads();

    float inv_[4][4];
#pragma unroll
    for (int mi = 0; mi < 4; ++mi)
#pragma unroll
        for (int r = 0; r < 4; ++r) {
            int row = mi * 16 + g * 4 + r;
            float t = 0.f;
#pragma unroll
            for (int w = 0; w < 8; ++w) t += red[w][row];
            inv_[mi][r] = 1.0f / t;
        }

    // ---- pass 2: recompute (B now L2-hot), scale, threshold, store ----
    float* ob = out + ((size_t)b * N_ + m0) * N_ + wave * 256;
#pragma unroll
    for (int ct = 0; ct < 16; ++ct) {
        short8 bfr[8];
#pragma unroll
        for (int ks = 0; ks < 8; ++ks)
            bfr[ks] = *(const short8*)(Kb + (size_t)(ct * 16 + cl) * COUT + ks * 32 + g * 8);
        f32x4 a[4];
#pragma unroll
        for (int mi = 0; mi < 4; ++mi) a[mi] = (f32x4)0.f;
#pragma unroll
        for (int ks = 0; ks < 8; ++ks)
#pragma unroll
            for (int mi = 0; mi < 4; ++mi)
                a[mi] = __builtin_amdgcn_mfma_f32_16x16x32_bf16(af[mi][ks], bfr[ks], a[mi], 0, 0, 0);
#pragma unroll
        for (int mi = 0; mi < 4; ++mi)
#pragma unroll
            for (int r = 0; r < 4; ++r) {
                float w = __expf((a[mi][r] - 1.0f) * SCALE_) * inv_[mi][r];
                w = (w > EPS_THR) ? w : 0.f;
                __builtin_nontemporal_store(w, &ob[(size_t)(mi * 16 + g * 4 + r) * N_ + ct * 16 + cl]);
            }
    }
}

// ---------------- K4: copy key to output tail ---------------------------------------
__global__ __launch_bounds__(256) void copy_key(const float* __restrict__ in,
                                                float* __restrict__ dst, int n4) {
    int i = blockIdx.x * 256 + threadIdx.x;
    if (i < n4) {
        f32x4 v = ((const f32x4*)in)[i];
        __builtin_nontemporal_store(v, &((f32x4*)dst)[i]);
    }
}

extern "C" void kernel_launch(void* const* d_in, const int* in_sizes, int n_in,
                              void* d_out, int out_size, void* d_ws, size_t ws_size,
                              hipStream_t stream) {
    const float* q  = (const float*)d_in[0];
    const float* k  = (const float*)d_in[1];
    const float* W1 = (const float*)d_in[2];
    const float* W2 = (const float*)d_in[3];
    float* out = (float*)d_out;

    // ws: W1b | W2b | QK  (17.3 MB)
    ushort* W1b = (ushort*)d_ws;
    ushort* W2b = W1b + 131072;
    ushort* QK  = W2b + 131072;                 // [32768][256] bf16

    // H scratch inside d_out (overwritten by scores_softmax later)
    ushort* H = (ushort*)d_out;                 // [32768][512] bf16, 33.5 MB

    prep_w<<<512, 256, 0, stream>>>(W1, W2, W1b, W2b);
    conv1_fused<<<512, 512, 0, stream>>>(q, k, W1b, H);
    conv2_norm<<<256, 512, 0, stream>>>(H, W2b, QK);
    scores_softmax<<<256, 512, 0, stream>>>(QK, out);
    copy_key<<<4096, 256, 0, stream>>>(k, out + (size_t)B_ * N_ * N_, (B_ * CIN * N_) / 4);
}

// Round 9
// 147.708 us; speedup vs baseline: 2.1152x; 2.1152x over previous
//
#include <hip/hip_runtime.h>
#include <hip/hip_bf16.h>
#include <math.h>

#define B_      8
#define CIN     256
#define CMID    512
#define COUT    256
#define N_      2048
#define SCALE_  10.0f
#define EPS_THR 1e-3f
#define NORM_EPS_ 1e-12f

typedef __attribute__((ext_vector_type(8))) short short8;
typedef __attribute__((ext_vector_type(4))) float f32x4;

__device__ __forceinline__ ushort f2bf(float x) {
    union { float f; uint u; } v; v.f = x;
    uint r = v.u + 0x7FFF + ((v.u >> 16) & 1);
    return (ushort)(r >> 16);
}
__device__ __forceinline__ float bf2f(ushort h) {
    union { uint u; float f; } v; v.u = ((uint)h) << 16;
    return v.f;
}
__device__ __forceinline__ void gload_lds16(const void* g, void* l) {
    __builtin_amdgcn_global_load_lds((const __attribute__((address_space(1))) void*)g,
                                     (__attribute__((address_space(3))) void*)l, 16, 0, 0);
}

// ---------------- K0: weights fp32 -> bf16 ------------------------------------------
__global__ __launch_bounds__(256) void prep_w(const float* __restrict__ W1,
                                              const float* __restrict__ W2,
                                              ushort* __restrict__ W1b,
                                              ushort* __restrict__ W2b) {
    int idx = blockIdx.x * 256 + threadIdx.x;   // 0..131071
    W1b[idx] = f2bf(W1[idx]);
    W2b[idx] = f2bf(W2[idx]);
}

// ---------------- K1: conv1 fused with input transpose ------------------------------
// XCD-aligned tile permutation: blocks with bid%8==b own batch-b rows, so H rows of
// batch b are written (dirty) into XCD b's L2 — same XCD that conv2/K3 read from.
#define ASTRIDE 40
__global__ __launch_bounds__(512) void conv1_fused(const float* __restrict__ q,
                                                   const float* __restrict__ k,
                                                   const ushort* __restrict__ W1b,
                                                   ushort* __restrict__ H) {
    __shared__ ushort As[64 * ASTRIDE];   // 5 KB, padded stride
    __shared__ ushort Bs[512 * 32];       // 32 KB
    int tid = threadIdx.x;
    int lane = tid & 63, wave = tid >> 6;
    int g = lane >> 4, cl = lane & 15;
    // permuted tile index: T = half*256 + b*32 + j  (b = bid%8 -> XCD b)
    int bx = blockIdx.x;
    int half = bx >> 8;
    int u = bx & 255;
    int pb = u & 7, pj = u >> 3;          // pj in [0,32)
    size_t m0 = ((size_t)half * 256 + (size_t)pb * 32 + pj) * 64;
    const float* xsrc = (m0 < 16384) ? q : k;
    int b = (int)((m0 >> 11) & 7);
    int nbase = (int)(m0 & 2047);
    const float* xp = xsrc + ((size_t)b * CIN + wave * 4) * N_ + nbase + lane;

    f32x4 acc[4][4];
#pragma unroll
    for (int i = 0; i < 4; ++i)
#pragma unroll
        for (int j = 0; j < 4; ++j) acc[i][j] = (f32x4)0.f;

    for (int k0 = 0; k0 < CIN; k0 += 32) {
#pragma unroll
        for (int si = 0; si < 4; ++si) {
            int s = tid + si * 512;
            gload_lds16(W1b + (size_t)(s >> 2) * CIN + k0 + (s & 3) * 8, Bs + s * 8);
        }
        float v0 = xp[(size_t)(k0 + 0) * N_];
        float v1 = xp[(size_t)(k0 + 1) * N_];
        float v2 = xp[(size_t)(k0 + 2) * N_];
        float v3 = xp[(size_t)(k0 + 3) * N_];
        ushort4 wv;
        wv.x = f2bf(v0); wv.y = f2bf(v1); wv.z = f2bf(v2); wv.w = f2bf(v3);
        *(ushort4*)&As[lane * ASTRIDE + wave * 4] = wv;
        __syncthreads();

        short8 af[4], bfr[4];
#pragma unroll
        for (int mi = 0; mi < 4; ++mi)
            af[mi] = *(const short8*)&As[(mi * 16 + cl) * ASTRIDE + g * 8];
#pragma unroll
        for (int ni = 0; ni < 4; ++ni)
            bfr[ni] = *(const short8*)&Bs[(wave * 64 + ni * 16 + cl) * 32 + g * 8];
#pragma unroll
        for (int mi = 0; mi < 4; ++mi)
#pragma unroll
            for (int ni = 0; ni < 4; ++ni)
                acc[mi][ni] = __builtin_amdgcn_mfma_f32_16x16x32_bf16(af[mi], bfr[ni], acc[mi][ni], 0, 0, 0);
        __syncthreads();
    }

#pragma unroll
    for (int mi = 0; mi < 4; ++mi)
#pragma unroll
        for (int ni = 0; ni < 4; ++ni)
#pragma unroll
            for (int r = 0; r < 4; ++r) {
                float v = acc[mi][ni][r];
                v = (v >= 0.f) ? v : 0.01f * v;
                H[(m0 + mi * 16 + g * 4 + r) * CMID + wave * 64 + ni * 16 + cl] = f2bf(v);
            }
}

// ---------------- K2: conv2 fused with row L2-norm ----------------------------------
// Same XCD-aligned permutation: QK rows of batch b written by bid%8==b blocks
// (XCD b), which also read batch-b H rows written there by conv1.
__global__ __launch_bounds__(512) void conv2_norm(const ushort* __restrict__ H,
                                                  const ushort* __restrict__ W2b,
                                                  ushort* __restrict__ QK) {
    __shared__ ushort As[128 * 32];   // 8 KB
    __shared__ ushort Bs[256 * 32];   // 16 KB
    __shared__ float red[4][128];     // 2 KB
    int tid = threadIdx.x;
    int lane = tid & 63, wave = tid >> 6;
    int wm = wave >> 2, wn = wave & 3;
    int g = lane >> 4, cl = lane & 15;
    // permuted tile index: T = half*128 + b*16 + j
    int bx = blockIdx.x;
    int half = bx >> 7;
    int u = bx & 127;
    int pb = u & 7, pj = u >> 3;          // pj in [0,16)
    size_t m0 = ((size_t)half * 128 + (size_t)pb * 16 + pj) * 128;

    f32x4 acc[4][4];
#pragma unroll
    for (int i = 0; i < 4; ++i)
#pragma unroll
        for (int j = 0; j < 4; ++j) acc[i][j] = (f32x4)0.f;

    for (int k0 = 0; k0 < CMID; k0 += 32) {
        gload_lds16(H + (m0 + (tid >> 2)) * CMID + k0 + (tid & 3) * 8, As + tid * 8);
#pragma unroll
        for (int si = 0; si < 2; ++si) {
            int s = tid + si * 512;
            gload_lds16(W2b + (size_t)(s >> 2) * CMID + k0 + (s & 3) * 8, Bs + s * 8);
        }
        __syncthreads();
        short8 af[4], bfr[4];
#pragma unroll
        for (int mi = 0; mi < 4; ++mi)
            af[mi] = *(const short8*)&As[(wm * 64 + mi * 16 + cl) * 32 + g * 8];
#pragma unroll
        for (int ni = 0; ni < 4; ++ni)
            bfr[ni] = *(const short8*)&Bs[(wn * 64 + ni * 16 + cl) * 32 + g * 8];
#pragma unroll
        for (int mi = 0; mi < 4; ++mi)
#pragma unroll
            for (int ni = 0; ni < 4; ++ni)
                acc[mi][ni] = __builtin_amdgcn_mfma_f32_16x16x32_bf16(af[mi], bfr[ni], acc[mi][ni], 0, 0, 0);
        __syncthreads();
    }

#pragma unroll
    for (int mi = 0; mi < 4; ++mi)
#pragma unroll
        for (int r = 0; r < 4; ++r) {
            float s = 0.f;
#pragma unroll
            for (int ni = 0; ni < 4; ++ni) { float v = acc[mi][ni][r]; s += v * v; }
#pragma unroll
            for (int off = 1; off < 16; off <<= 1) s += __shfl_xor(s, off, 64);
            if (cl == 0) red[wn][wm * 64 + mi * 16 + g * 4 + r] = s;
        }
    __syncthreads();
#pragma unroll
    for (int mi = 0; mi < 4; ++mi)
#pragma unroll
        for (int r = 0; r < 4; ++r) {
            int row = wm * 64 + mi * 16 + g * 4 + r;
            float tot = red[0][row] + red[1][row] + red[2][row] + red[3][row];
            float inv = 1.0f / fmaxf(sqrtf(tot), NORM_EPS_);
#pragma unroll
            for (int ni = 0; ni < 4; ++ni)
                QK[(m0 + row) * COUT + wn * 64 + ni * 16 + cl] = f2bf(acc[mi][ni][r] * inv);
        }
}

// ---------------- K3: fused scores + softmax(fixed max) + threshold -----------------
// R6 structure (best measured): 32 q-rows x 2048 k-cols, 8 waves, e in LDS bf16.
// b = bid&7 pins batch b to XCD b (round-robin dispatch), matching conv2's writers.
#define ESTRIDE 2052
__global__ __launch_bounds__(512, 2) void scores_softmax(const ushort* __restrict__ QK,
                                                         float* __restrict__ out) {
    __shared__ ushort eLDS[32 * ESTRIDE];   // 131328 B
    __shared__ float red[8][32];            // 1 KB
    int bid = blockIdx.x;
    int b = bid & 7;                 // batch-per-XCD swizzle
    int m0 = (bid >> 3) * 32;
    int tid = threadIdx.x;
    int lane = tid & 63, wave = tid >> 6;
    int g = lane >> 4, cl = lane & 15;

    const ushort* Qb = QK + ((size_t)b * N_ + m0) * COUT;
    const ushort* Kb = QK + ((size_t)16384 + (size_t)b * N_ + wave * 256) * COUT;

    short8 af0[8], af1[8];
#pragma unroll
    for (int ks = 0; ks < 8; ++ks) {
        af0[ks] = *(const short8*)(Qb + (size_t)cl * COUT + ks * 32 + g * 8);
        af1[ks] = *(const short8*)(Qb + (size_t)(16 + cl) * COUT + ks * 32 + g * 8);
    }

    float rs0[4] = {0.f, 0.f, 0.f, 0.f}, rs1[4] = {0.f, 0.f, 0.f, 0.f};
    int ecol = wave * 256 + cl;

#pragma unroll
    for (int ct = 0; ct < 16; ++ct) {
        f32x4 a0 = (f32x4)0.f, a1 = (f32x4)0.f;
#pragma unroll
        for (int ks = 0; ks < 8; ++ks) {
            short8 bfr = *(const short8*)(Kb + (size_t)(ct * 16 + cl) * COUT + ks * 32 + g * 8);
            a0 = __builtin_amdgcn_mfma_f32_16x16x32_bf16(af0[ks], bfr, a0, 0, 0, 0);
            a1 = __builtin_amdgcn_mfma_f32_16x16x32_bf16(af1[ks], bfr, a1, 0, 0, 0);
        }
#pragma unroll
        for (int r = 0; r < 4; ++r) {
            float e0 = __expf((a0[r] - 1.0f) * SCALE_);
            rs0[r] += e0;
            eLDS[(g * 4 + r) * ESTRIDE + ecol + ct * 16] = f2bf(e0);
            float e1 = __expf((a1[r] - 1.0f) * SCALE_);
            rs1[r] += e1;
            eLDS[(16 + g * 4 + r) * ESTRIDE + ecol + ct * 16] = f2bf(e1);
        }
    }

    // row sums: reduce over 16 cl lanes, then across 8 waves via LDS
#pragma unroll
    for (int r = 0; r < 4; ++r) {
        float s = rs0[r];
#pragma unroll
        for (int off = 1; off < 16; off <<= 1) s += __shfl_xor(s, off, 64);
        if (cl == 0) red[wave][g * 4 + r] = s;
        float s1 = rs1[r];
#pragma unroll
        for (int off = 1; off < 16; off <<= 1) s1 += __shfl_xor(s1, off, 64);
        if (cl == 0) red[wave][16 + g * 4 + r] = s1;
    }
    __syncthreads();

    // phase 2: wave w -> rows 4w..4w+3; scale, threshold, store
    float inv_[4];
#pragma unroll
    for (int rr = 0; rr < 4; ++rr) {
        int row = wave * 4 + rr;
        float t = 0.f;
#pragma unroll
        for (int w = 0; w < 8; ++w) t += red[w][row];
        inv_[rr] = 1.0f / t;
    }

    float* ob = out + (size_t)b * N_ * N_ + (size_t)m0 * N_;
#pragma unroll
    for (int rr = 0; rr < 4; ++rr) {
        int row = wave * 4 + rr;
        const ushort* ep = &eLDS[row * ESTRIDE];
        float* orow = ob + (size_t)row * N_;
#pragma unroll
        for (int j = 0; j < 8; ++j) {
            int c = j * 256 + lane * 4;
            ushort4 ev = *(const ushort4*)&ep[c];
            f32x4 w;
            float t;
            t = bf2f(ev.x) * inv_[rr]; w.x = (t > EPS_THR) ? t : 0.f;
            t = bf2f(ev.y) * inv_[rr]; w.y = (t > EPS_THR) ? t : 0.f;
            t = bf2f(ev.z) * inv_[rr]; w.z = (t > EPS_THR) ? t : 0.f;
            t = bf2f(ev.w) * inv_[rr]; w.w = (t > EPS_THR) ? t : 0.f;
            __builtin_nontemporal_store(w, (f32x4*)&orow[c]);
        }
    }
}

// ---------------- K4: copy key to output tail ---------------------------------------
__global__ __launch_bounds__(256) void copy_key(const float* __restrict__ in,
                                                float* __restrict__ dst, int n4) {
    int i = blockIdx.x * 256 + threadIdx.x;
    if (i < n4) {
        f32x4 v = ((const f32x4*)in)[i];
        __builtin_nontemporal_store(v, &((f32x4*)dst)[i]);
    }
}

extern "C" void kernel_launch(void* const* d_in, const int* in_sizes, int n_in,
                              void* d_out, int out_size, void* d_ws, size_t ws_size,
                              hipStream_t stream) {
    const float* q  = (const float*)d_in[0];
    const float* k  = (const float*)d_in[1];
    const float* W1 = (const float*)d_in[2];
    const float* W2 = (const float*)d_in[3];
    float* out = (float*)d_out;

    // ws: W1b | W2b | QK  (17.3 MB)
    ushort* W1b = (ushort*)d_ws;
    ushort* W2b = W1b + 131072;
    ushort* QK  = W2b + 131072;                 // [32768][256] bf16

    // H scratch inside d_out (overwritten by scores_softmax later)
    ushort* H = (ushort*)d_out;                 // [32768][512] bf16, 33.5 MB

    prep_w<<<512, 256, 0, stream>>>(W1, W2, W1b, W2b);
    conv1_fused<<<512, 512, 0, stream>>>(q, k, W1b, H);
    conv2_norm<<<256, 512, 0, stream>>>(H, W2b, QK);
    scores_softmax<<<512, 512, 0, stream>>>(QK, out);
    copy_key<<<4096, 256, 0, stream>>>(k, out + (size_t)B_ * N_ * N_, (B_ * CIN * N_) / 4);
}

// Round 10
// 107.086 us; speedup vs baseline: 2.9176x; 1.3793x over previous
//
#include <hip/hip_runtime.h>
#include <hip/hip_bf16.h>
#include <math.h>

#define B_      8
#define CIN     256
#define CMID    512
#define COUT    256
#define N_      2048
#define SCALE_  10.0f
#define EPS_THR 1e-3f
#define NORM_EPS_ 1e-12f

typedef __attribute__((ext_vector_type(8))) short short8;
typedef __attribute__((ext_vector_type(4))) float f32x4;

__device__ __forceinline__ ushort f2bf(float x) {
    union { float f; uint u; } v; v.f = x;
    uint r = v.u + 0x7FFF + ((v.u >> 16) & 1);
    return (ushort)(r >> 16);
}
__device__ __forceinline__ float bf2f(ushort h) {
    union { uint u; float f; } v; v.u = ((uint)h) << 16;
    return v.f;
}
__device__ __forceinline__ void gload_lds16(const void* g, void* l) {
    __builtin_amdgcn_global_load_lds((const __attribute__((address_space(1))) void*)g,
                                     (__attribute__((address_space(3))) void*)l, 16, 0, 0);
}

// ---------------- K0: weights fp32 -> bf16 ------------------------------------------
__global__ __launch_bounds__(256) void prep_w(const float* __restrict__ W1,
                                              const float* __restrict__ W2,
                                              ushort* __restrict__ W1b,
                                              ushort* __restrict__ W2b) {
    int idx = blockIdx.x * 256 + threadIdx.x;   // 0..131071
    W1b[idx] = f2bf(W1[idx]);
    W2b[idx] = f2bf(W2[idx]);
}

// ---------------- K1: conv1 fused with input transpose ------------------------------
#define ASTRIDE 40
__global__ __launch_bounds__(512) void conv1_fused(const float* __restrict__ q,
                                                   const float* __restrict__ k,
                                                   const ushort* __restrict__ W1b,
                                                   ushort* __restrict__ H) {
    __shared__ ushort As[64 * ASTRIDE];   // 5 KB, padded stride
    __shared__ ushort Bs[512 * 32];       // 32 KB
    int tid = threadIdx.x;
    int lane = tid & 63, wave = tid >> 6;
    int g = lane >> 4, cl = lane & 15;
    // XCD-aligned tile permutation (kept from R9; harmless)
    int bx = blockIdx.x;
    int half = bx >> 8;
    int u = bx & 255;
    int pb = u & 7, pj = u >> 3;          // pj in [0,32)
    size_t m0 = ((size_t)half * 256 + (size_t)pb * 32 + pj) * 64;
    const float* xsrc = (m0 < 16384) ? q : k;
    int b = (int)((m0 >> 11) & 7);
    int nbase = (int)(m0 & 2047);
    const float* xp = xsrc + ((size_t)b * CIN + wave * 4) * N_ + nbase + lane;

    f32x4 acc[4][4];
#pragma unroll
    for (int i = 0; i < 4; ++i)
#pragma unroll
        for (int j = 0; j < 4; ++j) acc[i][j] = (f32x4)0.f;

    for (int k0 = 0; k0 < CIN; k0 += 32) {
#pragma unroll
        for (int si = 0; si < 4; ++si) {
            int s = tid + si * 512;
            gload_lds16(W1b + (size_t)(s >> 2) * CIN + k0 + (s & 3) * 8, Bs + s * 8);
        }
        float v0 = xp[(size_t)(k0 + 0) * N_];
        float v1 = xp[(size_t)(k0 + 1) * N_];
        float v2 = xp[(size_t)(k0 + 2) * N_];
        float v3 = xp[(size_t)(k0 + 3) * N_];
        ushort4 wv;
        wv.x = f2bf(v0); wv.y = f2bf(v1); wv.z = f2bf(v2); wv.w = f2bf(v3);
        *(ushort4*)&As[lane * ASTRIDE + wave * 4] = wv;
        __syncthreads();

        short8 af[4], bfr[4];
#pragma unroll
        for (int mi = 0; mi < 4; ++mi)
            af[mi] = *(const short8*)&As[(mi * 16 + cl) * ASTRIDE + g * 8];
#pragma unroll
        for (int ni = 0; ni < 4; ++ni)
            bfr[ni] = *(const short8*)&Bs[(wave * 64 + ni * 16 + cl) * 32 + g * 8];
#pragma unroll
        for (int mi = 0; mi < 4; ++mi)
#pragma unroll
            for (int ni = 0; ni < 4; ++ni)
                acc[mi][ni] = __builtin_amdgcn_mfma_f32_16x16x32_bf16(af[mi], bfr[ni], acc[mi][ni], 0, 0, 0);
        __syncthreads();
    }

#pragma unroll
    for (int mi = 0; mi < 4; ++mi)
#pragma unroll
        for (int ni = 0; ni < 4; ++ni)
#pragma unroll
            for (int r = 0; r < 4; ++r) {
                float v = acc[mi][ni][r];
                v = (v >= 0.f) ? v : 0.01f * v;
                H[(m0 + mi * 16 + g * 4 + r) * CMID + wave * 64 + ni * 16 + cl] = f2bf(v);
            }
}

// ---------------- K2: conv2 fused with row L2-norm ----------------------------------
// Output QK in MFMA-FRAGMENT layout: element (row, kcol) stored at
//   (row>>4)*4096 + (kcol>>5)*512 + ((kcol>>3)&3)*128 + (row&15)*8 + (kcol&7)
// so a wave's A/B-fragment load (lane = g*16+cl) is panel*4096 + ks*512 + lane*8
// == one contiguous 1 KB transaction.
__global__ __launch_bounds__(512) void conv2_norm(const ushort* __restrict__ H,
                                                  const ushort* __restrict__ W2b,
                                                  ushort* __restrict__ QK) {
    __shared__ ushort As[128 * 32];   // 8 KB
    __shared__ ushort Bs[256 * 32];   // 16 KB
    __shared__ float red[4][128];     // 2 KB
    int tid = threadIdx.x;
    int lane = tid & 63, wave = tid >> 6;
    int wm = wave >> 2, wn = wave & 3;
    int g = lane >> 4, cl = lane & 15;
    // XCD-aligned tile permutation (kept from R9)
    int bx = blockIdx.x;
    int half = bx >> 7;
    int u = bx & 127;
    int pb = u & 7, pj = u >> 3;          // pj in [0,16)
    size_t m0 = ((size_t)half * 128 + (size_t)pb * 16 + pj) * 128;

    f32x4 acc[4][4];
#pragma unroll
    for (int i = 0; i < 4; ++i)
#pragma unroll
        for (int j = 0; j < 4; ++j) acc[i][j] = (f32x4)0.f;

    for (int k0 = 0; k0 < CMID; k0 += 32) {
        gload_lds16(H + (m0 + (tid >> 2)) * CMID + k0 + (tid & 3) * 8, As + tid * 8);
#pragma unroll
        for (int si = 0; si < 2; ++si) {
            int s = tid + si * 512;
            gload_lds16(W2b + (size_t)(s >> 2) * CMID + k0 + (s & 3) * 8, Bs + s * 8);
        }
        __syncthreads();
        short8 af[4], bfr[4];
#pragma unroll
        for (int mi = 0; mi < 4; ++mi)
            af[mi] = *(const short8*)&As[(wm * 64 + mi * 16 + cl) * 32 + g * 8];
#pragma unroll
        for (int ni = 0; ni < 4; ++ni)
            bfr[ni] = *(const short8*)&Bs[(wn * 64 + ni * 16 + cl) * 32 + g * 8];
#pragma unroll
        for (int mi = 0; mi < 4; ++mi)
#pragma unroll
            for (int ni = 0; ni < 4; ++ni)
                acc[mi][ni] = __builtin_amdgcn_mfma_f32_16x16x32_bf16(af[mi], bfr[ni], acc[mi][ni], 0, 0, 0);
        __syncthreads();
    }

#pragma unroll
    for (int mi = 0; mi < 4; ++mi)
#pragma unroll
        for (int r = 0; r < 4; ++r) {
            float s = 0.f;
#pragma unroll
            for (int ni = 0; ni < 4; ++ni) { float v = acc[mi][ni][r]; s += v * v; }
#pragma unroll
            for (int off = 1; off < 16; off <<= 1) s += __shfl_xor(s, off, 64);
            if (cl == 0) red[wn][wm * 64 + mi * 16 + g * 4 + r] = s;
        }
    __syncthreads();
#pragma unroll
    for (int mi = 0; mi < 4; ++mi)
#pragma unroll
        for (int r = 0; r < 4; ++r) {
            int row = wm * 64 + mi * 16 + g * 4 + r;
            size_t row_g = m0 + row;
            float tot = red[0][row] + red[1][row] + red[2][row] + red[3][row];
            float inv = 1.0f / fmaxf(sqrtf(tot), NORM_EPS_);
            size_t pbase = (row_g >> 4) * 4096 + (size_t)(row_g & 15) * 8;
#pragma unroll
            for (int ni = 0; ni < 4; ++ni) {
                int kcol = wn * 64 + ni * 16 + cl;
                size_t off = pbase + (size_t)(kcol >> 5) * 512
                           + (size_t)((kcol >> 3) & 3) * 128 + (kcol & 7);
                QK[off] = f2bf(acc[mi][ni][r] * inv);
            }
        }
}

// ---------------- K3: fused scores + softmax(fixed max) + threshold -----------------
// R6 structure; QK now in fragment layout => af/bfr loads are contiguous 1 KB
// per wave instruction (was 16-way-split 512B-strided before).
#define ESTRIDE 2052
__global__ __launch_bounds__(512, 2) void scores_softmax(const ushort* __restrict__ QK,
                                                         float* __restrict__ out) {
    __shared__ ushort eLDS[32 * ESTRIDE];   // 131328 B
    __shared__ float red[8][32];            // 1 KB
    int bid = blockIdx.x;
    int b = bid & 7;                 // batch-per-XCD swizzle
    int m0 = (bid >> 3) * 32;
    int tid = threadIdx.x;
    int lane = tid & 63, wave = tid >> 6;
    int g = lane >> 4, cl = lane & 15;

    // fragment-layout panels: 16 rows x 256 k = 4096 elems per panel
    const ushort* Qf = QK + ((size_t)(b * N_ + m0) >> 4) * 4096;
    const ushort* Kf = QK + ((size_t)(16384 + b * N_ + wave * 256) >> 4) * 4096;

    short8 af0[8], af1[8];
#pragma unroll
    for (int ks = 0; ks < 8; ++ks) {
        af0[ks] = *(const short8*)(Qf + ks * 512 + lane * 8);
        af1[ks] = *(const short8*)(Qf + 4096 + ks * 512 + lane * 8);
    }

    float rs0[4] = {0.f, 0.f, 0.f, 0.f}, rs1[4] = {0.f, 0.f, 0.f, 0.f};
    int ecol = wave * 256 + cl;

#pragma unroll
    for (int ct = 0; ct < 16; ++ct) {
        f32x4 a0 = (f32x4)0.f, a1 = (f32x4)0.f;
#pragma unroll
        for (int ks = 0; ks < 8; ++ks) {
            short8 bfr = *(const short8*)(Kf + (size_t)ct * 4096 + ks * 512 + lane * 8);
            a0 = __builtin_amdgcn_mfma_f32_16x16x32_bf16(af0[ks], bfr, a0, 0, 0, 0);
            a1 = __builtin_amdgcn_mfma_f32_16x16x32_bf16(af1[ks], bfr, a1, 0, 0, 0);
        }
#pragma unroll
        for (int r = 0; r < 4; ++r) {
            float e0 = __expf((a0[r] - 1.0f) * SCALE_);
            rs0[r] += e0;
            eLDS[(g * 4 + r) * ESTRIDE + ecol + ct * 16] = f2bf(e0);
            float e1 = __expf((a1[r] - 1.0f) * SCALE_);
            rs1[r] += e1;
            eLDS[(16 + g * 4 + r) * ESTRIDE + ecol + ct * 16] = f2bf(e1);
        }
    }

    // row sums: reduce over 16 cl lanes, then across 8 waves via LDS
#pragma unroll
    for (int r = 0; r < 4; ++r) {
        float s = rs0[r];
#pragma unroll
        for (int off = 1; off < 16; off <<= 1) s += __shfl_xor(s, off, 64);
        if (cl == 0) red[wave][g * 4 + r] = s;
        float s1 = rs1[r];
#pragma unroll
        for (int off = 1; off < 16; off <<= 1) s1 += __shfl_xor(s1, off, 64);
        if (cl == 0) red[wave][16 + g * 4 + r] = s1;
    }
    __syncthreads();

    // phase 2: wave w -> rows 4w..4w+3; scale, threshold, store
    float inv_[4];
#pragma unroll
    for (int rr = 0; rr < 4; ++rr) {
        int row = wave * 4 + rr;
        float t = 0.f;
#pragma unroll
        for (int w = 0; w < 8; ++w) t += red[w][row];
        inv_[rr] = 1.0f / t;
    }

    float* ob = out + (size_t)b * N_ * N_ + (size_t)m0 * N_;
#pragma unroll
    for (int rr = 0; rr < 4; ++rr) {
        int row = wave * 4 + rr;
        const ushort* ep = &eLDS[row * ESTRIDE];
        float* orow = ob + (size_t)row * N_;
#pragma unroll
        for (int j = 0; j < 8; ++j) {
            int c = j * 256 + lane * 4;
            ushort4 ev = *(const ushort4*)&ep[c];
            f32x4 w;
            float t;
            t = bf2f(ev.x) * inv_[rr]; w.x = (t > EPS_THR) ? t : 0.f;
            t = bf2f(ev.y) * inv_[rr]; w.y = (t > EPS_THR) ? t : 0.f;
            t = bf2f(ev.z) * inv_[rr]; w.z = (t > EPS_THR) ? t : 0.f;
            t = bf2f(ev.w) * inv_[rr]; w.w = (t > EPS_THR) ? t : 0.f;
            __builtin_nontemporal_store(w, (f32x4*)&orow[c]);
        }
    }
}

// ---------------- K4: copy key to output tail ---------------------------------------
__global__ __launch_bounds__(256) void copy_key(const float* __restrict__ in,
                                                float* __restrict__ dst, int n4) {
    int i = blockIdx.x * 256 + threadIdx.x;
    if (i < n4) {
        f32x4 v = ((const f32x4*)in)[i];
        __builtin_nontemporal_store(v, &((f32x4*)dst)[i]);
    }
}

extern "C" void kernel_launch(void* const* d_in, const int* in_sizes, int n_in,
                              void* d_out, int out_size, void* d_ws, size_t ws_size,
                              hipStream_t stream) {
    const float* q  = (const float*)d_in[0];
    const float* k  = (const float*)d_in[1];
    const float* W1 = (const float*)d_in[2];
    const float* W2 = (const float*)d_in[3];
    float* out = (float*)d_out;

    // ws: W1b | W2b | QK  (17.3 MB)
    ushort* W1b = (ushort*)d_ws;
    ushort* W2b = W1b + 131072;
    ushort* QK  = W2b + 131072;                 // [2048 panels][4096] bf16 (fragment layout)

    // H scratch inside d_out (overwritten by scores_softmax later)
    ushort* H = (ushort*)d_out;                 // [32768][512] bf16, 33.5 MB

    prep_w<<<512, 256, 0, stream>>>(W1, W2, W1b, W2b);
    conv1_fused<<<512, 512, 0, stream>>>(q, k, W1b, H);
    conv2_norm<<<256, 512, 0, stream>>>(H, W2b, QK);
    scores_softmax<<<512, 512, 0, stream>>>(QK, out);
    copy_key<<<4096, 256, 0, stream>>>(k, out + (size_t)B_ * N_ * N_, (B_ * CIN * N_) / 4);
}